// Round 6
// baseline (545.332 us; speedup 1.0000x reference)
//
#include <hip/hip_runtime.h>
#include <cmath>

// EstimatorQNNGen275: conv+sigmoid+mean -> 1-dim attention -> 4-layer tanh MLP
// (3x 512x4096x4096 GEMMs, fp16 MFMA, split-K=8, NO-LDS register-direct
// fragment streaming) -> pairwise-fidelity graph.
//
// R5 lesson: four different barrier-coupled LDS staging loops all plateau at
// ~70us with all pipes <10% busy — the barrier convoy is structural. This
// version has ZERO LDS and ZERO barriers in the K-loop: MFMA fragments are
// loaded straight from global (each wave-instr covers 16 rows x 64B lines,
// fully consumed), W converted fp32->fp16 in-register with depth-1 prefetch.
// Block-id map id = y*256 + x*8 + z pins the 4 y-siblings of each W K-slice
// to one XCD (XCD ~ id%8) so W reuse is served by that XCD's L2.
//
// ws layout (bytes):
//   [0,2048)     c_buf (512 f32)
//   [2048,4096)  attn  (512 f32)
//   [4096,4736)  D     (10 dot accumulators, line-padded stride 16 f32)
//   [8192,..)    act1 ; act2 ; act3 (f32, 8MB) ; part (8 x 8MB) ;
//                act1h ; act2h ; act3h (fp16, 4MB)

#define NEL (512 * 4096)

typedef float  floatx4 __attribute__((ext_vector_type(4)));
typedef _Float16 halfx8 __attribute__((ext_vector_type(8)));
typedef _Float16 halfx4 __attribute__((ext_vector_type(4)));

// ---------------- conv + sigmoid + mean (float4) ----------------
__global__ __launch_bounds__(256) void conv_mean_kernel(
    const float* __restrict__ x, const float* __restrict__ cw,
    const float* __restrict__ cb, float* __restrict__ c_out)
{
  __shared__ float sbuf[4];
  const int b = blockIdx.x;
  const float w00 = cw[0], w01 = cw[1], w10 = cw[2], w11 = cw[3];
  const float bias = cb[0];
  const float* xb = x + (size_t)b * 128 * 128;
  float acc = 0.f;
  for (int t = threadIdx.x; t < 127 * 32; t += 256) {
    const int i  = t >> 5;
    const int j0 = (t & 31) << 2;
    const float* pr0 = xb + i * 128 + j0;
    const float* pr1 = pr0 + 128;
    const float4 a4 = *reinterpret_cast<const float4*>(pr0);
    const float  a5 = pr0[4];
    const float4 b4 = *reinterpret_cast<const float4*>(pr1);
    const float  b5 = pr1[4];
    const float a[5] = {a4.x, a4.y, a4.z, a4.w, a5};
    const float bb[5] = {b4.x, b4.y, b4.z, b4.w, b5};
    #pragma unroll
    for (int m = 0; m < 4; ++m) {
      if (j0 + m < 127) {
        float v = w00 * a[m] + w01 * a[m + 1] + w10 * bb[m] + w11 * bb[m + 1] + bias;
        acc += 1.0f / (1.0f + __expf(-v));
      }
    }
  }
  #pragma unroll
  for (int off = 32; off > 0; off >>= 1) acc += __shfl_down(acc, off, 64);
  const int lane = threadIdx.x & 63, wv = threadIdx.x >> 6;
  if (lane == 0) sbuf[wv] = acc;
  __syncthreads();
  if (threadIdx.x == 0)
    c_out[b] = (sbuf[0] + sbuf[1] + sbuf[2] + sbuf[3]) * (1.0f / 16129.0f);
}

// ---------------- 1-dim attention ----------------
__global__ __launch_bounds__(64) void attn_kernel(
    const float* __restrict__ c, const float* __restrict__ rot,
    const float* __restrict__ ent, float* __restrict__ attn)
{
  const int i = blockIdx.x;
  const int lane = threadIdx.x;
  const float t = rot[0] * ent[0] * c[i];
  float vals[8], cj[8];
  float mx = -1e30f;
  #pragma unroll
  for (int u = 0; u < 8; ++u) {
    float cv = c[lane + u * 64];
    cj[u] = cv;
    vals[u] = t * cv;
    mx = fmaxf(mx, vals[u]);
  }
  #pragma unroll
  for (int off = 32; off > 0; off >>= 1) mx = fmaxf(mx, __shfl_down(mx, off, 64));
  mx = __shfl(mx, 0, 64);
  float se = 0.f, sw = 0.f;
  #pragma unroll
  for (int u = 0; u < 8; ++u) {
    float e = __expf(vals[u] - mx);
    se += e;
    sw += e * cj[u];
  }
  #pragma unroll
  for (int off = 32; off > 0; off >>= 1) {
    se += __shfl_down(se, off, 64);
    sw += __shfl_down(sw, off, 64);
  }
  if (lane == 0) attn[i] = sw / se;
}

// ---------------- layer 1 (outer product + tanh, dual-dtype out) -------------
__global__ __launch_bounds__(256) void layer1_kernel(
    const float* __restrict__ attn, const float* __restrict__ W1,
    const float* __restrict__ b1, float* __restrict__ act1,
    _Float16* __restrict__ act1h)
{
  const int o = blockIdx.x * 256 + threadIdx.x;
  const int i = blockIdx.y;
  const float v = tanhf(attn[i] * W1[o] + b1[o]);
  act1[(size_t)i * 4096 + o] = v;
  if (act1h) act1h[(size_t)i * 4096 + o] = (_Float16)v;
}

// ---------- fp16-MFMA GEMM, no LDS, no barriers, register-direct frags ------
// A: 512 x 4096 (fp16 if AHALF else fp32) row-major; W: 4096 x 4096 fp32.
// 256 thr = 4 waves (2x2); wave = 64x64 via 4x4 16x16x32 MFMA tiles.
// FUSE=false: id = y*256 + x*8 + z (z = K-slice & XCD), raw partial out.
// FUSE=true : id = y*32 + x, full K, tanh(acc+bias) out.
template<bool AHALF, bool FUSE>
__global__ __launch_bounds__(256, 3) void gemm_sk_kernel(
    const void* __restrict__ Av, const float* __restrict__ W,
    const float* __restrict__ bias, float* __restrict__ outp)
{
  const int K = 4096, N = 4096;
  const int id = blockIdx.x;
  int y, x, z, kbeg, kend;
  if (FUSE) { y = id >> 5; x = id & 31; z = 0; kbeg = 0; kend = K; }
  else      { y = id >> 8; x = (id >> 3) & 31; z = id & 7;
              kbeg = z * 512; kend = kbeg + 512; }
  const int tid = threadIdx.x, lane = tid & 63, wave = tid >> 6;
  const int wm = (wave >> 1) * 64, wn = (wave & 1) * 64;
  const int q = lane >> 4, ml = lane & 15;
  const int tileM = y * 128, tileN = x * 128;
  float* Cb = FUSE ? outp : outp + (size_t)z * NEL;

  const float* wRow = W + (size_t)(tileN + wn + ml) * K + q * 8;

  floatx4 acc[4][4] = {};
  halfx8 af[4], wf[4];
  float4 wr[8];

  auto loadW = [&](float4* d, int k0) {
    #pragma unroll
    for (int j = 0; j < 4; ++j) {
      const float* p = wRow + (size_t)j * 16 * K + k0;
      d[2 * j]     = *reinterpret_cast<const float4*>(p);
      d[2 * j + 1] = *reinterpret_cast<const float4*>(p + 4);
    }
  };
  auto cvtW = [&](halfx8* h, const float4* r) {
    #pragma unroll
    for (int j = 0; j < 4; ++j)
      h[j] = halfx8{ (_Float16)r[2*j].x,   (_Float16)r[2*j].y,
                     (_Float16)r[2*j].z,   (_Float16)r[2*j].w,
                     (_Float16)r[2*j+1].x, (_Float16)r[2*j+1].y,
                     (_Float16)r[2*j+1].z, (_Float16)r[2*j+1].w };
  };

  const _Float16* aRowH = nullptr;
  const float*    aRowF = nullptr;
  if (AHALF) aRowH = (const _Float16*)Av + (size_t)(tileM + wm + ml) * K + q * 8;
  else       aRowF = (const float*)Av    + (size_t)(tileM + wm + ml) * K + q * 8;

  auto loadA = [&](halfx8* d, int k0) {
    if (AHALF) {
      #pragma unroll
      for (int i = 0; i < 4; ++i)
        d[i] = *reinterpret_cast<const halfx8*>(aRowH + (size_t)i * 16 * K + k0);
    } else {
      #pragma unroll
      for (int i = 0; i < 4; ++i) {
        const float* p = aRowF + (size_t)i * 16 * K + k0;
        const float4 r0 = *reinterpret_cast<const float4*>(p);
        const float4 r1 = *reinterpret_cast<const float4*>(p + 4);
        d[i] = halfx8{ (_Float16)r0.x, (_Float16)r0.y, (_Float16)r0.z, (_Float16)r0.w,
                       (_Float16)r1.x, (_Float16)r1.y, (_Float16)r1.z, (_Float16)r1.w };
      }
    }
  };

  // prologue: one exposed W fetch for the first tile
  loadW(wr, kbeg);
  cvtW(wf, wr);

  for (int k0 = kbeg; k0 < kend; k0 += 32) {
    const bool more = (k0 + 32 < kend);
    loadA(af, k0);                 // on-demand (L1/L2-warm); issued before wr
    if (more) loadW(wr, k0 + 32);  // depth-1 prefetch, consumed after MFMAs

    #pragma unroll
    for (int i = 0; i < 4; ++i)
      #pragma unroll
      for (int j = 0; j < 4; ++j)
        acc[i][j] = __builtin_amdgcn_mfma_f32_16x16x32_f16(af[i], wf[j], acc[i][j], 0, 0, 0);

    if (more) cvtW(wf, wr);        // vmcnt wait lands a full MFMA block after issue
  }

  // C/D layout: col=lane&15, row=(lane>>4)*4+reg
  #pragma unroll
  for (int i = 0; i < 4; ++i) {
    const int row0 = tileM + wm + i * 16 + q * 4;
    #pragma unroll
    for (int j = 0; j < 4; ++j) {
      const int col = tileN + wn + j * 16 + ml;
      if (FUSE) {
        const float bv = bias[col];
        #pragma unroll
        for (int r = 0; r < 4; ++r)
          Cb[(size_t)(row0 + r) * N + col] = tanhf(acc[i][j][r] + bv);
      } else {
        #pragma unroll
        for (int r = 0; r < 4; ++r)
          Cb[(size_t)(row0 + r) * N + col] = acc[i][j][r];
      }
    }
  }
}

// ---------------- split-K combine: sum 8 slices + bias + tanh ----------------
template<bool WRITEH>
__global__ __launch_bounds__(256) void combine_tanh_kernel(
    const float* __restrict__ part, const float* __restrict__ bias,
    float* __restrict__ outp, _Float16* __restrict__ outh)
{
  const int i4 = blockIdx.x * 256 + threadIdx.x;  // < NEL/4
  const floatx4* p4 = (const floatx4*)part;
  floatx4 s = p4[i4];
  #pragma unroll
  for (int zz = 1; zz < 8; ++zz) s += p4[(size_t)zz * (NEL / 4) + i4];
  const floatx4 bv = ((const floatx4*)bias)[i4 & 1023];
  floatx4 o;
  #pragma unroll
  for (int r = 0; r < 4; ++r) o[r] = tanhf(s[r] + bv[r]);
  ((floatx4*)outp)[i4] = o;
  if (WRITEH) {
    halfx4 h = { (_Float16)o[0], (_Float16)o[1], (_Float16)o[2], (_Float16)o[3] };
    ((halfx4*)outh)[i4] = h;
  }
}

// ---------------- fid pairwise dots (low-contention) ----------------
__global__ __launch_bounds__(256) void fid_dots_kernel(
    const float* __restrict__ a1, const float* __restrict__ a2,
    const float* __restrict__ a3, const float* __restrict__ a4,
    float* __restrict__ D)
{
  __shared__ float sred[4][10];
  float s[10] = {0, 0, 0, 0, 0, 0, 0, 0, 0, 0};
  const int n4 = NEL / 4;
  const int stride = gridDim.x * blockDim.x;
  const floatx4* p1 = (const floatx4*)a1;
  const floatx4* p2 = (const floatx4*)a2;
  const floatx4* p3 = (const floatx4*)a3;
  const floatx4* p4 = (const floatx4*)a4;
  for (int i = blockIdx.x * 256 + threadIdx.x; i < n4; i += stride) {
    floatx4 v1 = p1[i], v2 = p2[i], v3 = p3[i], v4 = p4[i];
    #pragma unroll
    for (int r = 0; r < 4; ++r) {
      s[0] += v1[r] * v1[r]; s[1] += v1[r] * v2[r]; s[2] += v1[r] * v3[r];
      s[3] += v1[r] * v4[r]; s[4] += v2[r] * v2[r]; s[5] += v2[r] * v3[r];
      s[6] += v2[r] * v4[r]; s[7] += v3[r] * v3[r]; s[8] += v3[r] * v4[r];
      s[9] += v4[r] * v4[r];
    }
  }
  const int lane = threadIdx.x & 63, wv = threadIdx.x >> 6;
  #pragma unroll
  for (int p = 0; p < 10; ++p) {
    float v = s[p];
    #pragma unroll
    for (int off = 32; off > 0; off >>= 1) v += __shfl_down(v, off, 64);
    if (lane == 0) sred[wv][p] = v;
  }
  __syncthreads();
  if (threadIdx.x < 10) {
    float v = sred[0][threadIdx.x] + sred[1][threadIdx.x] +
              sred[2][threadIdx.x] + sred[3][threadIdx.x];
    atomicAdd(&D[threadIdx.x * 16], v);
  }
}

// ---------------- finalize graph weights ----------------
__global__ void finalize_kernel(const float* __restrict__ D, float* __restrict__ wout)
{
  const int i = threadIdx.x;
  if (i >= 16) return;
  const int p = i >> 2, qq = i & 3;
  const int a = p < qq ? p : qq;
  const int b = p < qq ? qq : p;
  const int base[4] = {0, 4, 7, 9};
  const float dpq = D[(base[a] + (b - a)) * 16];
  const float npv = sqrtf(D[base[p] * 16]) + 1e-12f;
  const float nqv = sqrtf(D[base[qq] * 16]) + 1e-12f;
  const float ch = dpq / (npv * nqv);
  const float fid = ch * ch;
  wout[i] = (fid >= 0.8f && p != qq) ? 1.0f : 0.0f;
}

extern "C" void kernel_launch(void* const* d_in, const int* in_sizes, int n_in,
                              void* d_out, int out_size, void* d_ws, size_t ws_size,
                              hipStream_t stream)
{
  const float* x   = (const float*)d_in[0];
  const float* cw  = (const float*)d_in[1];
  const float* cb  = (const float*)d_in[2];
  const float* rot = (const float*)d_in[3];
  const float* ent = (const float*)d_in[4];
  const float* W1  = (const float*)d_in[5];
  const float* b1  = (const float*)d_in[6];
  const float* W2  = (const float*)d_in[7];
  const float* b2  = (const float*)d_in[8];
  const float* W3  = (const float*)d_in[9];
  const float* b3  = (const float*)d_in[10];
  const float* W4  = (const float*)d_in[11];
  const float* b4  = (const float*)d_in[12];
  float* out = (float*)d_out;

  char*  ws    = (char*)d_ws;
  float* c_buf = (float*)(ws + 0);
  float* attn  = (float*)(ws + 2048);
  float* D     = (float*)(ws + 4096);
  float* act1  = (float*)(ws + 8192);
  float* act2  = act1 + NEL;
  float* act3  = act2 + NEL;
  float* part  = act3 + NEL;                    // 8 x NEL fp32
  _Float16* act1h = (_Float16*)(part + (size_t)8 * NEL);
  _Float16* act2h = act1h + NEL;
  _Float16* act3h = act2h + NEL;
  float* wout  = out + NEL;

  const size_t need = 8192 + (size_t)3 * NEL * 4 + (size_t)8 * NEL * 4
                    + (size_t)3 * NEL * 2;
  const bool sk = ws_size >= need;

  hipMemsetAsync(D, 0, 10 * 16 * sizeof(float), stream);
  conv_mean_kernel<<<512, 256, 0, stream>>>(x, cw, cb, c_buf);
  attn_kernel<<<512, 64, 0, stream>>>(c_buf, rot, ent, attn);
  layer1_kernel<<<dim3(16, 512), 256, 0, stream>>>(attn, W1, b1, act1,
                                                   sk ? act1h : nullptr);

  const int cgrid = NEL / 4 / 256;
  if (sk) {
    gemm_sk_kernel<true,false><<<1024, 256, 0, stream>>>(act1h, W2, nullptr, part);
    combine_tanh_kernel<true><<<cgrid, 256, 0, stream>>>(part, b2, act2, act2h);
    gemm_sk_kernel<true,false><<<1024, 256, 0, stream>>>(act2h, W3, nullptr, part);
    combine_tanh_kernel<true><<<cgrid, 256, 0, stream>>>(part, b3, act3, act3h);
    gemm_sk_kernel<true,false><<<1024, 256, 0, stream>>>(act3h, W4, nullptr, part);
    combine_tanh_kernel<false><<<cgrid, 256, 0, stream>>>(part, b4, out, nullptr);
  } else {
    gemm_sk_kernel<false,true><<<128, 256, 0, stream>>>(act1, W2, b2, act2);
    gemm_sk_kernel<false,true><<<128, 256, 0, stream>>>(act2, W3, b3, act3);
    gemm_sk_kernel<false,true><<<128, 256, 0, stream>>>(act3, W4, b4, out);
  }

  fid_dots_kernel<<<512, 256, 0, stream>>>(act1, act2, act3, out, D);
  finalize_kernel<<<1, 64, 0, stream>>>(D, wout);
}